// Round 8
// baseline (8898.109 us; speedup 1.0000x reference)
//
#include <hip/hip_runtime.h>

typedef _Float16 f16;
typedef _Float16 f16x2 __attribute__((ext_vector_type(2)));
typedef _Float16 f16x4 __attribute__((ext_vector_type(4)));
typedef _Float16 f16x8 __attribute__((ext_vector_type(8)));
typedef float f32x4 __attribute__((ext_vector_type(4)));

#define AS1 __attribute__((address_space(1)))
#define AS3 __attribute__((address_space(3)))

static __device__ __forceinline__ float sigf(float x) { return 1.f / (1.f + __expf(-x)); }
static __device__ __forceinline__ float tanh_f(float x) { return 2.f / (1.f + __expf(-2.f * x)) - 1.f; }

// ---------------- fp32 -> fp16 ----------------
__global__ void f2h_kernel(const float* __restrict__ in, f16* __restrict__ out, int n4) {
  const int i = blockIdx.x * blockDim.x + threadIdx.x;
  if (i >= n4) return;
  const float4 v = ((const float4*)in)[i];
  f16x4 o;
  o[0] = (f16)v.x; o[1] = (f16)v.y; o[2] = (f16)v.z; o[3] = (f16)v.w;
  ((f16x4*)out)[i] = o;
}

__global__ void bias_kernel(const float* __restrict__ a, const float* __restrict__ b,
                            float* __restrict__ o, int n) {
  const int i = blockIdx.x * blockDim.x + threadIdx.x;
  if (i < n) o[i] = a[i] + b[i];
}

// ---------------- xg GEMM:  out[dir][row][g] = A[row,:]·Bt[dir*2048+g,:] + bias ----------------
__global__ __launch_bounds__(256) void gemm_xg(const f16* __restrict__ A,
                                               const f16* __restrict__ Bt,
                                               const float* __restrict__ bias,
                                               f16* __restrict__ outp, int K) {
  __shared__ f16 As[128 * 64];
  __shared__ f16 Bs[128 * 64];
  const int tid = threadIdx.x;
  const int w = tid >> 6, l = tid & 63;
  const int m0 = blockIdx.x << 7, n0 = blockIdx.y << 7;
  const int wm = w >> 1, wn = w & 1;
  f32x4 acc[4][4] = {};

  const int lr8 = l >> 3, lc8 = l & 7;
  const int gcol = (lc8 ^ lr8) << 3;

  for (int k0 = 0; k0 < K; k0 += 64) {
    __syncthreads();
#pragma unroll
    for (int j = 0; j < 4; ++j) {
      const int i = (w << 2) + j;
      const f16* ga = A + (size_t)(m0 + (i << 3) + lr8) * K + (k0 + gcol);
      __builtin_amdgcn_global_load_lds((const AS1 void*)ga, (AS3 void*)(As + (i << 9)), 16, 0, 0);
      const f16* gb = Bt + (size_t)(n0 + (i << 3) + lr8) * K + (k0 + gcol);
      __builtin_amdgcn_global_load_lds((const AS1 void*)gb, (AS3 void*)(Bs + (i << 9)), 16, 0, 0);
    }
    asm volatile("s_waitcnt vmcnt(0)" ::: "memory");
    __syncthreads();

#pragma unroll
    for (int kk = 0; kk < 2; ++kk) {
      const int cb = (kk << 6) + ((l >> 4) << 4);
      f16x8 af[4], bf[4];
#pragma unroll
      for (int a = 0; a < 4; ++a) {
        const int r = (wm << 6) + (a << 4) + (l & 15);
        af[a] = *(const f16x8*)((const char*)As + r * 128 + (cb ^ ((r & 7) << 4)));
      }
#pragma unroll
      for (int b = 0; b < 4; ++b) {
        const int r = (wn << 6) + (b << 4) + (l & 15);
        bf[b] = *(const f16x8*)((const char*)Bs + r * 128 + (cb ^ ((r & 7) << 4)));
      }
#pragma unroll
      for (int a = 0; a < 4; ++a)
#pragma unroll
        for (int b = 0; b < 4; ++b)
          acc[a][b] = __builtin_amdgcn_mfma_f32_16x16x32_f16(af[a], bf[b], acc[a][b], 0, 0, 0);
    }
  }

#pragma unroll
  for (int b = 0; b < 4; ++b) {
    const int col = n0 + (wn << 6) + (b << 4) + (l & 15);
    const float bv = bias[col];
    f16* ob = outp + (size_t)(col >> 11) * (16384ull * 2048) + (col & 2047);
#pragma unroll
    for (int a = 0; a < 4; ++a) {
      const int row0 = m0 + (wm << 6) + (a << 4) + ((l >> 4) << 2);
#pragma unroll
      for (int r = 0; r < 4; ++r)
        ob[(size_t)(row0 + r) * 2048] = (f16)(acc[a][b][r] + bv);
    }
  }
}

// ---------------- persistent bidirectional LSTM scan (one layer) ----------------
// 256 WGs launched; only blockIdx%8<2 kept (dir = blockIdx%8, s = blockIdx>>3):
// under round-robin dispatch, each dir's 32 WGs land on ONE XCD (shared L2).
// Publish is dual: (a) agent-scope ring {tag=t, data} (R3-proven, ALWAYS valid),
// (b) plain store to a mirror {tag=t^data, data} that stays in the XCD's L2.
// Consumers first poll the mirror with sc0 loads (L1-bypass, L2-served, ~0.2us)
// for K bounded rounds, then fall back to the R3 agent-ring loop for leftovers.
// Mis-colocation only wastes the K rounds (finite); correctness never depends on
// the mirror. Stale mirror data from a prior replay is deterministically identical
// (same inputs => same h), and memset-0 state fails the xor checksum => rejected.
__global__ __launch_bounds__(256) void lstm_scan(const f16* __restrict__ Whb,   // [2][2048][512]
                                                 const f16* __restrict__ xg,    // [2][16384][2048]
                                                 unsigned long long* __restrict__ ring,   // [2][4][32][256]
                                                 unsigned long long* __restrict__ mir,    // [2][4][32][256]
                                                 f16* __restrict__ h0_all,      // [16384][1024] (layer0)
                                                 float* __restrict__ outf,      // [16384][1024] (layer1)
                                                 float* __restrict__ hn,        // [4][32][512]
                                                 float* __restrict__ cn,        // [4][32][512]
                                                 const int layer) {
  __shared__ f16 Wh_s[64 * 512];      // 64 KB, XOR-swizzled rows
  __shared__ f16 h_s[32 * 512];       // 32 KB, XOR-swizzled rows
  __shared__ float G_s[4 * 32 * 18];  // 9 KB gate exchange, stride 18

  const int xslot = blockIdx.x & 7;
  if (xslot > 1) return;              // keep 64 of 256 WGs (2 XCDs' worth)
  const int dir = xslot;
  const int s = blockIdx.x >> 3;

  const int tid = threadIdx.x;
  const int w = tid >> 6, l = tid & 63;

  // load Wh slice: local row lr=16g+u <- Whb row dir*2048 + 512g + 16s + u (wave-coalesced)
#pragma unroll
  for (int j = 0; j < 16; ++j) {
    const int chunk = (j << 8) + tid;
    const int lr = chunk >> 6;
    const int cbyte = (chunk & 63) << 4;
    const int g = lr >> 4, u = lr & 15;
    const char* src = (const char*)Whb + (((size_t)dir * 2048 + (g << 9) + (s << 4) + u) << 10) + cbyte;
    const uint4 v = *(const uint4*)src;
    *(uint4*)((char*)Wh_s + (lr << 10) + (cbyte ^ ((lr & 7) << 4))) = v;
  }

  unsigned long long* rdir = ring + ((size_t)dir << 15);  // 4*32*256 entries per dir
  unsigned long long* mdir = mir + ((size_t)dir << 15);
  const int bb = tid >> 3;  // batch row 0..31
  const int up = tid & 7;   // unit pair -> units 2up, 2up+1

  float c0 = 0.f, c1 = 0.f;
  __syncthreads();

#pragma unroll 1
  for (int t = 0; t < 512; ++t) {
    const int tau = dir ? (511 - t) : t;
    // xg loads first (R3-proven position)
    const f16* xr = xg + (((size_t)dir * 16384 + (size_t)bb * 512 + (size_t)tau) << 11) + (s << 4) + (up << 1);
    const f16x2 xv0 = *(const f16x2*)(xr);
    const f16x2 xv1 = *(const f16x2*)(xr + 512);
    const f16x2 xv2 = *(const f16x2*)(xr + 1024);
    const f16x2 xv3 = *(const f16x2*)(xr + 1536);

    float pi0 = 0.f, pi1 = 0.f, pf0 = 0.f, pf1 = 0.f, pg0 = 0.f, pg1 = 0.f, po0 = 0.f, po1 = 0.f;

    if (t > 0) {
      const unsigned tgt = (unsigned)t;
      const size_t soff = (size_t)(t & 3) << 13;
      const unsigned long long* ms = mdir + soff;
      const unsigned long long* rs = rdir + soff;
      unsigned long long v[8][4];
      bool ok[8];
#pragma unroll
      for (int j = 0; j < 8; ++j) ok[j] = false;
      int remaining = 8;

      // ---- fast path: K bounded rounds of sc0 mirror polls (XCD-L2 served) ----
      for (int r = 0; r < 6 && remaining; ++r) {
#pragma unroll
        for (int j = 0; j < 8; ++j) {
          if (!ok[j]) {
            const int chunk = (j << 8) + tid;
            const unsigned long long* sp = ms + ((chunk >> 6) << 8) + ((chunk & 63) << 2);
#pragma unroll
            for (int q = 0; q < 4; ++q)
              asm volatile("global_load_dwordx2 %0, %1, off sc0" : "=v"(v[j][q]) : "v"(sp + q));
          }
        }
        asm volatile("s_waitcnt vmcnt(0)" ::: "memory");
        __builtin_amdgcn_sched_barrier(0);
#pragma unroll
        for (int j = 0; j < 8; ++j) {
          if (!ok[j]) {
            if ((((unsigned)v[j][0] ^ (unsigned)(v[j][0] >> 32)) == tgt) &
                (((unsigned)v[j][1] ^ (unsigned)(v[j][1] >> 32)) == tgt) &
                (((unsigned)v[j][2] ^ (unsigned)(v[j][2] >> 32)) == tgt) &
                (((unsigned)v[j][3] ^ (unsigned)(v[j][3] >> 32)) == tgt)) {
              ok[j] = true;
              --remaining;
            }
          }
        }
      }

      // ---- fallback: R3-proven agent-ring poll for leftover chunks ----
      if (remaining) {
#pragma unroll
        for (int j = 0; j < 8; ++j) {
          if (!ok[j]) {
            const int chunk = (j << 8) + tid;
            const unsigned long long* sp = rs + ((chunk >> 6) << 8) + ((chunk & 63) << 2);
#pragma unroll
            for (int q = 0; q < 4; ++q)
              v[j][q] = __hip_atomic_load(sp + q, __ATOMIC_RELAXED, __HIP_MEMORY_SCOPE_AGENT);
          }
        }
#pragma unroll
        for (int j = 0; j < 8; ++j) {
          if (!ok[j]) {
            const int chunk = (j << 8) + tid;
            const unsigned long long* sp = rs + ((chunk >> 6) << 8) + ((chunk & 63) << 2);
            int guard = 0;
            while (!(((unsigned)v[j][0] == tgt) & ((unsigned)v[j][1] == tgt) &
                     ((unsigned)v[j][2] == tgt) & ((unsigned)v[j][3] == tgt))) {
#pragma unroll
              for (int q = 0; q < 4; ++q)
                v[j][q] = __hip_atomic_load(sp + q, __ATOMIC_RELAXED, __HIP_MEMORY_SCOPE_AGENT);
              if (++guard > (1 << 20)) break;
            }
          }
        }
      }

      // stage to LDS (XOR-swizzled); data is hi32 in BOTH mirror and ring formats
#pragma unroll
      for (int j = 0; j < 8; ++j) {
        const int chunk = (j << 8) + tid;
        const int b = chunk >> 6;
        uint4 d;
        d.x = (unsigned)(v[j][0] >> 32);
        d.y = (unsigned)(v[j][1] >> 32);
        d.z = (unsigned)(v[j][2] >> 32);
        d.w = (unsigned)(v[j][3] >> 32);
        const int cbyte = (chunk & 63) << 4;
        *(uint4*)((char*)h_s + (b << 10) + (cbyte ^ ((b & 7) << 4))) = d;
      }
      __syncthreads();

      // G[b, 16w+u] = sum_k h[b,k] * WhS[16w+u, k]   (wave w owns gate w)
      f32x4 acc0 = {}, acc1 = {};
#pragma unroll
      for (int kk = 0; kk < 16; ++kk) {
        const int cb = (kk << 6) + ((l >> 4) << 4);
        const int ra0 = l & 15;
        const int ra1 = 16 + ra0;
        const int rb = (w << 4) + ra0;
        const f16x8 a0 = *(const f16x8*)((const char*)h_s + (ra0 << 10) + (cb ^ ((ra0 & 7) << 4)));
        const f16x8 a1 = *(const f16x8*)((const char*)h_s + (ra1 << 10) + (cb ^ ((ra1 & 7) << 4)));
        const f16x8 bv = *(const f16x8*)((const char*)Wh_s + (rb << 10) + (cb ^ ((rb & 7) << 4)));
        acc0 = __builtin_amdgcn_mfma_f32_16x16x32_f16(a0, bv, acc0, 0, 0, 0);
        acc1 = __builtin_amdgcn_mfma_f32_16x16x32_f16(a1, bv, acc1, 0, 0, 0);
      }
#pragma unroll
      for (int r = 0; r < 4; ++r) {
        const int dr = ((l >> 4) << 2) + r;
        G_s[((w << 5) + dr) * 18 + (l & 15)] = acc0[r];
        G_s[((w << 5) + 16 + dr) * 18 + (l & 15)] = acc1[r];
      }
      __syncthreads();

      const float* gp = G_s + bb * 18 + (up << 1);
      const float2 vi = *(const float2*)(gp);
      const float2 vf = *(const float2*)(gp + 576);
      const float2 vg = *(const float2*)(gp + 1152);
      const float2 vo = *(const float2*)(gp + 1728);
      pi0 = vi.x; pi1 = vi.y; pf0 = vf.x; pf1 = vf.y;
      pg0 = vg.x; pg1 = vg.y; po0 = vo.x; po1 = vo.y;
    }

    pi0 += (float)xv0[0]; pi1 += (float)xv0[1];
    pf0 += (float)xv1[0]; pf1 += (float)xv1[1];
    pg0 += (float)xv2[0]; pg1 += (float)xv2[1];
    po0 += (float)xv3[0]; po1 += (float)xv3[1];

    const float i0 = sigf(pi0), i1 = sigf(pi1);
    const float f0 = sigf(pf0), f1 = sigf(pf1);
    const float g0 = tanh_f(pg0), g1 = tanh_f(pg1);
    const float o0 = sigf(po0), o1 = sigf(po1);
    c0 = f0 * c0 + i0 * g0;
    c1 = f1 * c1 + i1 * g1;
    const float h0v = o0 * tanh_f(c0);
    const float h1v = o1 * tanh_f(c1);

    union { f16x2 h2; unsigned u; } pk;
    pk.h2[0] = (f16)h0v; pk.h2[1] = (f16)h1v;

    // dual publish: mirror (plain, XCD-L2) + ring (agent, coherence point)
    {
      const size_t ridx = ((size_t)((t + 1) & 3) << 13) + ((size_t)bb << 8) + (s << 3) + up;
      const unsigned long long mv =
          ((unsigned long long)pk.u << 32) | (unsigned long long)((unsigned)(t + 1) ^ pk.u);
      mdir[ridx] = mv;  // plain store: write-through L1 -> shared XCD L2
      const unsigned long long pv = ((unsigned long long)pk.u << 32) | (unsigned long long)(t + 1);
      __hip_atomic_store(rdir + ridx, pv, __ATOMIC_RELAXED, __HIP_MEMORY_SCOPE_AGENT);
    }

    // epilogue stores (R3-proven per-step position)
    const size_t orow = (((size_t)bb * 512 + (size_t)tau) << 10) + ((size_t)dir << 9) + (s << 4) + (up << 1);
    if (layer == 0) {
      *(unsigned*)(h0_all + orow) = pk.u;
    } else {
      *(float2*)(outf + orow) = make_float2(h0v, h1v);
    }
    if (t == 511) {
      const size_t nidx = (((size_t)(layer << 1) + (size_t)dir) << 14) + ((size_t)bb << 9) + (s << 4) + (up << 1);
      *(float2*)(hn + nidx) = make_float2(h0v, h1v);
      *(float2*)(cn + nidx) = make_float2(c0, c1);
    }
  }
}

// ---------------- host ----------------
extern "C" void kernel_launch(void* const* d_in, const int* in_sizes, int n_in,
                              void* d_out, int out_size, void* d_ws, size_t ws_size,
                              hipStream_t stream) {
  const float* x = (const float*)d_in[0];
  const float* Wx0 = (const float*)d_in[1];
  const float* Wh0 = (const float*)d_in[2];
  const float* bx0 = (const float*)d_in[3];
  const float* bh0 = (const float*)d_in[4];
  const float* Wx1 = (const float*)d_in[5];
  const float* Wh1 = (const float*)d_in[6];
  const float* bx1 = (const float*)d_in[7];
  const float* bh1 = (const float*)d_in[8];

  char* ws = (char*)d_ws;
  size_t off = 0;
  auto alloc = [&](size_t b) { char* p = ws + off; off += (b + 255) & ~(size_t)255; return p; };
  f16* xg = (f16*)alloc(2ull * 16384 * 2048 * 2);      // 134 MB (reused both layers)
  f16* x_h = (f16*)alloc(16384ull * 512 * 2);
  f16* h0a = (f16*)alloc(16384ull * 1024 * 2);
  f16* Wx0h = (f16*)alloc(2ull * 2048 * 512 * 2);
  f16* Wh0h = (f16*)alloc(2ull * 2048 * 512 * 2);
  f16* Wx1h = (f16*)alloc(2ull * 2048 * 1024 * 2);
  f16* Wh1h = (f16*)alloc(2ull * 2048 * 512 * 2);
  float* bias0 = (float*)alloc(4096 * 4);
  float* bias1 = (float*)alloc(4096 * 4);
  const size_t RB = 2ull * 4 * 32 * 256 * 8;           // 512 KB per buffer
  unsigned long long* ring0 = (unsigned long long*)alloc(RB);
  unsigned long long* ring1 = (unsigned long long*)alloc(RB);
  unsigned long long* mir0 = (unsigned long long*)alloc(RB);
  unsigned long long* mir1 = (unsigned long long*)alloc(RB);
  if (off > ws_size) return;  // needs ~208 MB of workspace

  float* outp = (float*)d_out;
  float* hn = outp + 16384ull * 1024;
  float* cn = hn + 4ull * 32 * 512;

  // clear rings + mirrors (contiguous allocs -> one memset covers all four)
  hipMemsetAsync(ring0, 0, 4 * ((RB + 255) & ~(size_t)255), stream);

  f2h_kernel<<<dim3(2097152 / 256), 256, 0, stream>>>(x, x_h, 2097152);
  f2h_kernel<<<dim3(524288 / 256), 256, 0, stream>>>(Wx0, Wx0h, 524288);
  f2h_kernel<<<dim3(524288 / 256), 256, 0, stream>>>(Wh0, Wh0h, 524288);
  f2h_kernel<<<dim3(1048576 / 256), 256, 0, stream>>>(Wx1, Wx1h, 1048576);
  f2h_kernel<<<dim3(524288 / 256), 256, 0, stream>>>(Wh1, Wh1h, 524288);
  bias_kernel<<<16, 256, 0, stream>>>(bx0, bh0, bias0, 4096);
  bias_kernel<<<16, 256, 0, stream>>>(bx1, bh1, bias1, 4096);

  dim3 g(128, 32);
  gemm_xg<<<g, 256, 0, stream>>>(x_h, Wx0h, bias0, xg, 512);
  lstm_scan<<<256, 256, 0, stream>>>(Wh0h, xg, ring0, mir0, h0a, nullptr, hn, cn, 0);
  gemm_xg<<<g, 256, 0, stream>>>(h0a, Wx1h, bias1, xg, 1024);
  lstm_scan<<<256, 256, 0, stream>>>(Wh1h, xg, ring1, mir1, nullptr, outp, hn, cn, 1);
}

// Round 9
// 8481.058 us; speedup vs baseline: 1.0492x; 1.0492x over previous
//
#include <hip/hip_runtime.h>

typedef _Float16 f16;
typedef _Float16 f16x2 __attribute__((ext_vector_type(2)));
typedef _Float16 f16x4 __attribute__((ext_vector_type(4)));
typedef _Float16 f16x8 __attribute__((ext_vector_type(8)));
typedef float f32x4 __attribute__((ext_vector_type(4)));

#define AS1 __attribute__((address_space(1)))
#define AS3 __attribute__((address_space(3)))

static __device__ __forceinline__ float sigf(float x) { return 1.f / (1.f + __expf(-x)); }
static __device__ __forceinline__ float tanh_f(float x) { return 2.f / (1.f + __expf(-2.f * x)) - 1.f; }

// ---------------- fp32 -> fp16 ----------------
__global__ void f2h_kernel(const float* __restrict__ in, f16* __restrict__ out, int n4) {
  const int i = blockIdx.x * blockDim.x + threadIdx.x;
  if (i >= n4) return;
  const float4 v = ((const float4*)in)[i];
  f16x4 o;
  o[0] = (f16)v.x; o[1] = (f16)v.y; o[2] = (f16)v.z; o[3] = (f16)v.w;
  ((f16x4*)out)[i] = o;
}

__global__ void bias_kernel(const float* __restrict__ a, const float* __restrict__ b,
                            float* __restrict__ o, int n) {
  const int i = blockIdx.x * blockDim.x + threadIdx.x;
  if (i < n) o[i] = a[i] + b[i];
}

// ---------------- xg GEMM:  out[dir][row][g] = A[row,:]·Bt[dir*2048+g,:] + bias ----------------
__global__ __launch_bounds__(256) void gemm_xg(const f16* __restrict__ A,
                                               const f16* __restrict__ Bt,
                                               const float* __restrict__ bias,
                                               f16* __restrict__ outp, int K) {
  __shared__ f16 As[128 * 64];
  __shared__ f16 Bs[128 * 64];
  const int tid = threadIdx.x;
  const int w = tid >> 6, l = tid & 63;
  const int m0 = blockIdx.x << 7, n0 = blockIdx.y << 7;
  const int wm = w >> 1, wn = w & 1;
  f32x4 acc[4][4] = {};

  const int lr8 = l >> 3, lc8 = l & 7;
  const int gcol = (lc8 ^ lr8) << 3;

  for (int k0 = 0; k0 < K; k0 += 64) {
    __syncthreads();
#pragma unroll
    for (int j = 0; j < 4; ++j) {
      const int i = (w << 2) + j;
      const f16* ga = A + (size_t)(m0 + (i << 3) + lr8) * K + (k0 + gcol);
      __builtin_amdgcn_global_load_lds((const AS1 void*)ga, (AS3 void*)(As + (i << 9)), 16, 0, 0);
      const f16* gb = Bt + (size_t)(n0 + (i << 3) + lr8) * K + (k0 + gcol);
      __builtin_amdgcn_global_load_lds((const AS1 void*)gb, (AS3 void*)(Bs + (i << 9)), 16, 0, 0);
    }
    asm volatile("s_waitcnt vmcnt(0)" ::: "memory");
    __syncthreads();

#pragma unroll
    for (int kk = 0; kk < 2; ++kk) {
      const int cb = (kk << 6) + ((l >> 4) << 4);
      f16x8 af[4], bf[4];
#pragma unroll
      for (int a = 0; a < 4; ++a) {
        const int r = (wm << 6) + (a << 4) + (l & 15);
        af[a] = *(const f16x8*)((const char*)As + r * 128 + (cb ^ ((r & 7) << 4)));
      }
#pragma unroll
      for (int b = 0; b < 4; ++b) {
        const int r = (wn << 6) + (b << 4) + (l & 15);
        bf[b] = *(const f16x8*)((const char*)Bs + r * 128 + (cb ^ ((r & 7) << 4)));
      }
#pragma unroll
      for (int a = 0; a < 4; ++a)
#pragma unroll
        for (int b = 0; b < 4; ++b)
          acc[a][b] = __builtin_amdgcn_mfma_f32_16x16x32_f16(af[a], bf[b], acc[a][b], 0, 0, 0);
    }
  }

#pragma unroll
  for (int b = 0; b < 4; ++b) {
    const int col = n0 + (wn << 6) + (b << 4) + (l & 15);
    const float bv = bias[col];
    f16* ob = outp + (size_t)(col >> 11) * (16384ull * 2048) + (col & 2047);
#pragma unroll
    for (int a = 0; a < 4; ++a) {
      const int row0 = m0 + (wm << 6) + (a << 4) + ((l >> 4) << 2);
#pragma unroll
      for (int r = 0; r < 4; ++r)
        ob[(size_t)(row0 + r) * 2048] = (f16)(acc[a][b][r] + bv);
    }
  }
}

// ---------------- persistent bidirectional LSTM scan (one layer) ----------------
// 64 WGs; each WG owns 8 units of dir0 AND 8 units of dir1 (fwd/rev time-share one
// WG set). Per round: full R3-proven step body for d0, then for d1. Each dir's
// publish->next-poll gap is filled by the other dir's phase, hiding most of the
// agent-scope (L3 coherence point) visibility latency. Sync protocol is EXACTLY
// R3's: 8B {tag=epoch, data} entries, 4-slot ring, burst + chunk-serial verify,
// bounded guards, no fences, no new coherence assumptions.
__global__ __launch_bounds__(256) void lstm_scan(const f16* __restrict__ Whb,   // [2][2048][512]
                                                 const f16* __restrict__ xg,    // [2][16384][2048]
                                                 unsigned long long* __restrict__ ring,  // [2][4][32][256]
                                                 f16* __restrict__ h0_all,      // [16384][1024] (layer0)
                                                 float* __restrict__ outf,      // [16384][1024] (layer1)
                                                 float* __restrict__ hn,        // [4][32][512]
                                                 float* __restrict__ cn,        // [4][32][512]
                                                 const int layer) {
  __shared__ f16 Wh_s[2 * 32 * 512];  // 64 KB: [dir][lr=g*8+u][512], XOR-swizzled rows
  __shared__ f16 h_s[32 * 512];       // 32 KB, sequentially shared by the two dirs
  __shared__ float G_s[32 * 36];      // 4.6 KB gate exchange, stride 36 (<=2-way banks)

  const int tid = threadIdx.x;
  const int s6 = blockIdx.x;          // 0..63: unit slice (8 units per dir)
  const int l = tid & 63;
  const int w = tid >> 6;
  const int wm = w >> 1, wn = w & 1;  // batch-half, gate-row-half

  // Wh load: 2 dirs x 32 rows (lr = g*8+u -> Whb row 512g + 8*s6 + u) x 64 16B-chunks
#pragma unroll
  for (int j = 0; j < 16; ++j) {
    const int c = (j << 8) + tid;
    const int d = c >> 11;
    const int lr = (c >> 6) & 31;
    const int cb = (c & 63) << 4;
    const int g = lr >> 3, u = lr & 7;
    const char* src = (const char*)Whb + (((size_t)d * 2048 + (g << 9) + (s6 << 3) + u) << 10) + cb;
    const uint4 v = *(const uint4*)src;
    *(uint4*)((char*)Wh_s + (d << 15) + (lr << 10) + (cb ^ ((lr & 7) << 4))) = v;
  }

  const int bb = tid >> 3;  // batch row 0..31
  const int uu = tid & 7;   // unit 0..7 (one unit per thread per dir)
  float cst0 = 0.f, cst1 = 0.f;
  __syncthreads();

#pragma unroll 1
  for (int t = 0; t < 512; ++t) {
#pragma unroll
    for (int d = 0; d < 2; ++d) {
      const int tau = d ? (511 - t) : t;
      // xg loads first (R3-proven position; retires under the poll)
      const f16* xr = xg + (((size_t)d * 16384 + (size_t)bb * 512 + (size_t)tau) << 11) + (s6 << 3) + uu;
      float pi = (float)xr[0];
      float pf = (float)xr[512];
      float pg = (float)xr[1024];
      float po = (float)xr[1536];
      unsigned long long* rdir = ring + ((size_t)d << 15);

      if (t > 0) {
        const unsigned tgt = (unsigned)t;
        const unsigned long long* rs = rdir + ((size_t)(t & 3) << 13);
        unsigned long long v[8][4];
        // optimistic burst: all 32 independent 8B loads
#pragma unroll
        for (int j = 0; j < 8; ++j) {
          const int c = (j << 8) + tid;
          const unsigned long long* sp = rs + ((c >> 6) << 8) + ((c & 63) << 2);
#pragma unroll
          for (int q = 0; q < 4; ++q)
            v[j][q] = __hip_atomic_load(sp + q, __ATOMIC_RELAXED, __HIP_MEMORY_SCOPE_AGENT);
        }
        // chunk-serial verify/retry (R3-proven), stage to LDS (XOR-swizzled)
#pragma unroll
        for (int j = 0; j < 8; ++j) {
          const int c = (j << 8) + tid;
          const int b = c >> 6;
          const unsigned long long* sp = rs + (b << 8) + ((c & 63) << 2);
          int guard = 0;
          while (!(((unsigned)v[j][0] == tgt) & ((unsigned)v[j][1] == tgt) &
                   ((unsigned)v[j][2] == tgt) & ((unsigned)v[j][3] == tgt))) {
#pragma unroll
            for (int q = 0; q < 4; ++q)
              v[j][q] = __hip_atomic_load(sp + q, __ATOMIC_RELAXED, __HIP_MEMORY_SCOPE_AGENT);
            if (++guard > (1 << 20)) break;
          }
          uint4 dd;
          dd.x = (unsigned)(v[j][0] >> 32);
          dd.y = (unsigned)(v[j][1] >> 32);
          dd.z = (unsigned)(v[j][2] >> 32);
          dd.w = (unsigned)(v[j][3] >> 32);
          const int cb = (c & 63) << 4;
          *(uint4*)((char*)h_s + (b << 10) + (cb ^ ((b & 7) << 4))) = dd;
        }
        __syncthreads();

        // MFMA: G[b, lr] = sum_k h[b,k] * Wh_s[d][lr,k]; M=32 (batch) x N=32 (gate-rows)
        f32x4 acc = {};
#pragma unroll
        for (int kk = 0; kk < 16; ++kk) {
          const int cb = (kk << 6) + ((l >> 4) << 4);
          const int ra = (wm << 4) + (l & 15);
          const int rb = (wn << 4) + (l & 15);
          const f16x8 av = *(const f16x8*)((const char*)h_s + (ra << 10) + (cb ^ ((ra & 7) << 4)));
          const f16x8 bv = *(const f16x8*)((const char*)Wh_s + (d << 15) + (rb << 10) + (cb ^ ((rb & 7) << 4)));
          acc = __builtin_amdgcn_mfma_f32_16x16x32_f16(av, bv, acc, 0, 0, 0);
        }
#pragma unroll
        for (int r = 0; r < 4; ++r)
          G_s[((wm << 4) + ((l >> 4) << 2) + r) * 36 + (wn << 4) + (l & 15)] = acc[r];
        __syncthreads();

        const float* gp = G_s + bb * 36 + uu;  // cols lr = g*8+uu
        pi += gp[0];
        pf += gp[8];
        pg += gp[16];
        po += gp[24];
      }

      const float iv = sigf(pi), fv = sigf(pf), gv = tanh_f(pg), ov = sigf(po);
      float& cs = d ? cst1 : cst0;
      cs = fv * cs + iv * gv;
      const float hv = ov * tanh_f(cs);

      // pack unit pair via wave shuffle (lanes tid, tid^1 are units uu, uu^1)
      union { f16 h; unsigned short us; } hb;
      hb.h = (f16)hv;
      const unsigned mine = hb.us;
      const unsigned other = (unsigned)__shfl_xor((int)mine, 1);
      const unsigned pk = (other << 16) | mine;          // valid on even-uu lanes
      const float hod = __shfl_xor(hv, 1);               // odd unit's f32 h (even lanes)

      // publish h_{t+1}: even threads store one 8B {tag,data} pair entry
      if (!(uu & 1)) {
        const size_t ridx = ((size_t)((t + 1) & 3) << 13) + ((size_t)bb << 8) + (s6 << 2) + (uu >> 1);
        const unsigned long long pv = ((unsigned long long)pk << 32) | (unsigned long long)(t + 1);
        __hip_atomic_store(rdir + ridx, pv, __ATOMIC_RELAXED, __HIP_MEMORY_SCOPE_AGENT);
      }

      // epilogue (off the critical path)
      const size_t orow = (((size_t)bb * 512 + (size_t)tau) << 10) + ((size_t)d << 9) + (s6 << 3) + uu;
      if (layer == 0) {
        if (!(uu & 1)) *(unsigned*)(h0_all + orow) = pk;
      } else {
        if (!(uu & 1)) *(float2*)(outf + orow) = make_float2(hv, hod);
      }
      if (t == 511) {
        const size_t nidx = (((size_t)(layer << 1) + (size_t)d) << 14) + (size_t)bb * 512 + (s6 << 3) + uu;
        hn[nidx] = hv;
        cn[nidx] = cs;
      }
    }
  }
}

// ---------------- host ----------------
extern "C" void kernel_launch(void* const* d_in, const int* in_sizes, int n_in,
                              void* d_out, int out_size, void* d_ws, size_t ws_size,
                              hipStream_t stream) {
  const float* x = (const float*)d_in[0];
  const float* Wx0 = (const float*)d_in[1];
  const float* Wh0 = (const float*)d_in[2];
  const float* bx0 = (const float*)d_in[3];
  const float* bh0 = (const float*)d_in[4];
  const float* Wx1 = (const float*)d_in[5];
  const float* Wh1 = (const float*)d_in[6];
  const float* bx1 = (const float*)d_in[7];
  const float* bh1 = (const float*)d_in[8];

  char* ws = (char*)d_ws;
  size_t off = 0;
  auto alloc = [&](size_t b) { char* p = ws + off; off += (b + 255) & ~(size_t)255; return p; };
  f16* xg = (f16*)alloc(2ull * 16384 * 2048 * 2);      // 134 MB (reused both layers)
  f16* x_h = (f16*)alloc(16384ull * 512 * 2);
  f16* h0a = (f16*)alloc(16384ull * 1024 * 2);
  f16* Wx0h = (f16*)alloc(2ull * 2048 * 512 * 2);
  f16* Wh0h = (f16*)alloc(2ull * 2048 * 512 * 2);
  f16* Wx1h = (f16*)alloc(2ull * 2048 * 1024 * 2);
  f16* Wh1h = (f16*)alloc(2ull * 2048 * 512 * 2);
  float* bias0 = (float*)alloc(4096 * 4);
  float* bias1 = (float*)alloc(4096 * 4);
  const size_t RB = 2ull * 4 * 32 * 256 * 8;           // 512 KB per layer ring
  unsigned long long* ring0 = (unsigned long long*)alloc(RB);
  unsigned long long* ring1 = (unsigned long long*)alloc(RB);
  if (off > ws_size) return;  // needs ~207 MB of workspace

  float* outp = (float*)d_out;
  float* hn = outp + 16384ull * 1024;
  float* cn = hn + 4ull * 32 * 512;

  // clear ring tags (stale tags from a previous replay would alias epochs);
  // ring0/ring1 are contiguous 256-aligned allocs -> one memset covers both
  hipMemsetAsync(ring0, 0, 2 * RB, stream);

  f2h_kernel<<<dim3(2097152 / 256), 256, 0, stream>>>(x, x_h, 2097152);
  f2h_kernel<<<dim3(524288 / 256), 256, 0, stream>>>(Wx0, Wx0h, 524288);
  f2h_kernel<<<dim3(524288 / 256), 256, 0, stream>>>(Wh0, Wh0h, 524288);
  f2h_kernel<<<dim3(1048576 / 256), 256, 0, stream>>>(Wx1, Wx1h, 1048576);
  f2h_kernel<<<dim3(524288 / 256), 256, 0, stream>>>(Wh1, Wh1h, 524288);
  bias_kernel<<<16, 256, 0, stream>>>(bx0, bh0, bias0, 4096);
  bias_kernel<<<16, 256, 0, stream>>>(bx1, bh1, bias1, 4096);

  dim3 g(128, 32);
  gemm_xg<<<g, 256, 0, stream>>>(x_h, Wx0h, bias0, xg, 512);
  lstm_scan<<<64, 256, 0, stream>>>(Wh0h, xg, ring0, h0a, nullptr, hn, cn, 0);
  gemm_xg<<<g, 256, 0, stream>>>(h0a, Wx1h, bias1, xg, 1024);
  lstm_scan<<<64, 256, 0, stream>>>(Wh1h, xg, ring1, nullptr, outp, hn, cn, 1);
}

// Round 10
// 5697.757 us; speedup vs baseline: 1.5617x; 1.4885x over previous
//
#include <hip/hip_runtime.h>

typedef _Float16 f16;
typedef _Float16 f16x2 __attribute__((ext_vector_type(2)));
typedef _Float16 f16x4 __attribute__((ext_vector_type(4)));
typedef _Float16 f16x8 __attribute__((ext_vector_type(8)));
typedef float f32x4 __attribute__((ext_vector_type(4)));

#define AS1 __attribute__((address_space(1)))
#define AS3 __attribute__((address_space(3)))

static __device__ __forceinline__ float sigf(float x) { return 1.f / (1.f + __expf(-x)); }
static __device__ __forceinline__ float tanh_f(float x) { return 2.f / (1.f + __expf(-2.f * x)) - 1.f; }

// ---------------- fp32 -> fp16 ----------------
__global__ void f2h_kernel(const float* __restrict__ in, f16* __restrict__ out, int n4) {
  const int i = blockIdx.x * blockDim.x + threadIdx.x;
  if (i >= n4) return;
  const float4 v = ((const float4*)in)[i];
  f16x4 o;
  o[0] = (f16)v.x; o[1] = (f16)v.y; o[2] = (f16)v.z; o[3] = (f16)v.w;
  ((f16x4*)out)[i] = o;
}

__global__ void bias_kernel(const float* __restrict__ a, const float* __restrict__ b,
                            float* __restrict__ o, int n) {
  const int i = blockIdx.x * blockDim.x + threadIdx.x;
  if (i < n) o[i] = a[i] + b[i];
}

// ---------------- xg GEMM:  out[dir][row][g] = A[row,:]·Bt[dir*2048+g,:] + bias ----------------
__global__ __launch_bounds__(256) void gemm_xg(const f16* __restrict__ A,
                                               const f16* __restrict__ Bt,
                                               const float* __restrict__ bias,
                                               f16* __restrict__ outp, int K) {
  __shared__ f16 As[128 * 64];
  __shared__ f16 Bs[128 * 64];
  const int tid = threadIdx.x;
  const int w = tid >> 6, l = tid & 63;
  const int m0 = blockIdx.x << 7, n0 = blockIdx.y << 7;
  const int wm = w >> 1, wn = w & 1;
  f32x4 acc[4][4] = {};

  const int lr8 = l >> 3, lc8 = l & 7;
  const int gcol = (lc8 ^ lr8) << 3;

  for (int k0 = 0; k0 < K; k0 += 64) {
    __syncthreads();
#pragma unroll
    for (int j = 0; j < 4; ++j) {
      const int i = (w << 2) + j;
      const f16* ga = A + (size_t)(m0 + (i << 3) + lr8) * K + (k0 + gcol);
      __builtin_amdgcn_global_load_lds((const AS1 void*)ga, (AS3 void*)(As + (i << 9)), 16, 0, 0);
      const f16* gb = Bt + (size_t)(n0 + (i << 3) + lr8) * K + (k0 + gcol);
      __builtin_amdgcn_global_load_lds((const AS1 void*)gb, (AS3 void*)(Bs + (i << 9)), 16, 0, 0);
    }
    asm volatile("s_waitcnt vmcnt(0)" ::: "memory");
    __syncthreads();

#pragma unroll
    for (int kk = 0; kk < 2; ++kk) {
      const int cb = (kk << 6) + ((l >> 4) << 4);
      f16x8 af[4], bf[4];
#pragma unroll
      for (int a = 0; a < 4; ++a) {
        const int r = (wm << 6) + (a << 4) + (l & 15);
        af[a] = *(const f16x8*)((const char*)As + r * 128 + (cb ^ ((r & 7) << 4)));
      }
#pragma unroll
      for (int b = 0; b < 4; ++b) {
        const int r = (wn << 6) + (b << 4) + (l & 15);
        bf[b] = *(const f16x8*)((const char*)Bs + r * 128 + (cb ^ ((r & 7) << 4)));
      }
#pragma unroll
      for (int a = 0; a < 4; ++a)
#pragma unroll
        for (int b = 0; b < 4; ++b)
          acc[a][b] = __builtin_amdgcn_mfma_f32_16x16x32_f16(af[a], bf[b], acc[a][b], 0, 0, 0);
    }
  }

#pragma unroll
  for (int b = 0; b < 4; ++b) {
    const int col = n0 + (wn << 6) + (b << 4) + (l & 15);
    const float bv = bias[col];
    f16* ob = outp + (size_t)(col >> 11) * (16384ull * 2048) + (col & 2047);
#pragma unroll
    for (int a = 0; a < 4; ++a) {
      const int row0 = m0 + (wm << 6) + (a << 4) + ((l >> 4) << 2);
#pragma unroll
      for (int r = 0; r < 4; ++r)
        ob[(size_t)(row0 + r) * 2048] = (f16)(acc[a][b][r] + bv);
    }
  }
}

// ---------------- persistent bidirectional LSTM scan (one layer) ----------------
// grid: 64 WGs = 2 dirs x 32 unit-slices. Wh slice in LDS. R3's ring protocol,
// byte-identical: 8B {tag=epoch, data} entries, 4-slot ring, burst + chunk-serial
// verify, bounded guards, no fences.
// R10 restructure (shorten the post-arrival critical tail):
//  - wave w owns units 4w..4w+3 with ALL 4 gates -> gate->cell exchange is
//    wave-private LDS (lgkmcnt wait, NO __syncthreads) -> one barrier/step total
//  - h_s double-buffered (parity t&1) so the single post-staging barrier is safe
//    (poll gating bounds wave skew to 1 step; alternating buffers kill WAR)
//  - xg(t+1) prefetched right after the staging barrier (retires under MFMA/cell)
__global__ __launch_bounds__(256) void lstm_scan(const f16* __restrict__ Whb,   // [2][2048][512]
                                                 const f16* __restrict__ xg,    // [2][16384][2048]
                                                 unsigned long long* __restrict__ ring,  // [2][4][32][256]
                                                 f16* __restrict__ h0_all,      // [16384][1024] (layer0)
                                                 float* __restrict__ outf,      // [16384][1024] (layer1)
                                                 float* __restrict__ hn,        // [4][32][512]
                                                 float* __restrict__ cn,        // [4][32][512]
                                                 const int layer) {
  __shared__ f16 Wh_s[64 * 512];       // 64 KB, XOR-swizzled rows (lr = 16g+u)
  __shared__ f16 h_s[2][32 * 512];     // 2 x 32 KB, XOR-swizzled rows, parity-buffered
  __shared__ float G_s[4][32 * 20];    // 10 KB: per-wave [32 b][20] (16 used: c=v*4+g)

  const int tid = threadIdx.x;
  const int dir = blockIdx.x >> 5;
  const int s = blockIdx.x & 31;
  const int w = tid >> 6, l = tid & 63;

  // load Wh slice: local row lr=16g+u <- Whb row dir*2048 + 512g + 16s + u (wave-coalesced)
#pragma unroll
  for (int j = 0; j < 16; ++j) {
    const int chunk = (j << 8) + tid;
    const int lr = chunk >> 6;
    const int cbyte = (chunk & 63) << 4;
    const int g = lr >> 4, u = lr & 15;
    const char* src = (const char*)Whb + (((size_t)dir * 2048 + (g << 9) + (s << 4) + u) << 10) + cbyte;
    const uint4 v = *(const uint4*)src;
    *(uint4*)((char*)Wh_s + (lr << 10) + (cbyte ^ ((lr & 7) << 4))) = v;
  }

  unsigned long long* rdir = ring + ((size_t)dir << 15);  // 4*32*256 entries per dir
  const int b32 = l & 31;                   // my batch row (cell/publish)
  const int vp = l >> 5;                    // unit-pair in wave: units 4w+2vp, +1
  const int ug = (s << 4) + (w << 2) + (vp << 1);  // global even unit index
  float* Gw = (float*)&G_s[w][0];

  float c0 = 0.f, c1 = 0.f;
  __syncthreads();

  // xg prefetch for t=0
  const f16* xr0 = xg + (((size_t)dir * 16384 + (size_t)b32 * 512 + (dir ? 511 : 0)) << 11) + ug;
  f16x2 xc0 = *(const f16x2*)(xr0);
  f16x2 xc1 = *(const f16x2*)(xr0 + 512);
  f16x2 xc2 = *(const f16x2*)(xr0 + 1024);
  f16x2 xc3 = *(const f16x2*)(xr0 + 1536);

#pragma unroll 1
  for (int t = 0; t < 512; ++t) {
    const int tau = dir ? (511 - t) : t;
    float pi0 = 0.f, pi1 = 0.f, pf0 = 0.f, pf1 = 0.f, pg0 = 0.f, pg1 = 0.f, po0 = 0.f, po1 = 0.f;

    if (t > 0) {
      const unsigned tgt = (unsigned)t;
      const unsigned long long* rs = rdir + ((size_t)(t & 3) << 13);
      unsigned long long v[8][4];
      // optimistic burst: all 32 independent 8B loads (R3-proven)
#pragma unroll
      for (int j = 0; j < 8; ++j) {
        const int chunk = (j << 8) + tid;
        const unsigned long long* sp = rs + ((chunk >> 6) << 8) + ((chunk & 63) << 2);
#pragma unroll
        for (int q = 0; q < 4; ++q)
          v[j][q] = __hip_atomic_load(sp + q, __ATOMIC_RELAXED, __HIP_MEMORY_SCOPE_AGENT);
      }
      // chunk-serial verify/retry, stage to h_s[t&1] (XOR-swizzled)
      char* hb = (char*)&h_s[t & 1][0];
#pragma unroll
      for (int j = 0; j < 8; ++j) {
        const int chunk = (j << 8) + tid;
        const int b = chunk >> 6;
        const unsigned long long* sp = rs + (b << 8) + ((chunk & 63) << 2);
        int guard = 0;
        while (!(((unsigned)v[j][0] == tgt) & ((unsigned)v[j][1] == tgt) &
                 ((unsigned)v[j][2] == tgt) & ((unsigned)v[j][3] == tgt))) {
#pragma unroll
          for (int q = 0; q < 4; ++q)
            v[j][q] = __hip_atomic_load(sp + q, __ATOMIC_RELAXED, __HIP_MEMORY_SCOPE_AGENT);
          if (++guard > (1 << 20)) break;
        }
        uint4 d;
        d.x = (unsigned)(v[j][0] >> 32);
        d.y = (unsigned)(v[j][1] >> 32);
        d.z = (unsigned)(v[j][2] >> 32);
        d.w = (unsigned)(v[j][3] >> 32);
        const int cbyte = (chunk & 63) << 4;
        *(uint4*)(hb + (b << 10) + (cbyte ^ ((b & 7) << 4))) = d;
      }
      __syncthreads();  // the ONLY barrier per step
    }

    // prefetch xg(t+1) now: retires under MFMA/G/cell, queue clean at next poll
    f16x2 xn0, xn1, xn2, xn3;
    {
      const int t2 = (t < 511) ? (t + 1) : t;
      const int tau2 = dir ? (511 - t2) : t2;
      const f16* xr = xg + (((size_t)dir * 16384 + (size_t)b32 * 512 + tau2) << 11) + ug;
      xn0 = *(const f16x2*)(xr);
      xn1 = *(const f16x2*)(xr + 512);
      xn2 = *(const f16x2*)(xr + 1024);
      xn3 = *(const f16x2*)(xr + 1536);
    }

    if (t > 0) {
      const char* hb = (const char*)&h_s[t & 1][0];
      // MFMA: wave w -> units 4w..4w+3, all gates. B rows rb = 16g + 4w + v.
      f32x4 acc0 = {}, acc1 = {};
#pragma unroll
      for (int kk = 0; kk < 16; ++kk) {
        const int cb = (kk << 6) + ((l >> 4) << 4);
        const int n = l & 15;
        const int ra0 = n;
        const int ra1 = 16 + n;
        const int rb = ((n >> 2) << 4) + (w << 2) + (n & 3);
        const f16x8 a0 = *(const f16x8*)(hb + (ra0 << 10) + (cb ^ ((ra0 & 7) << 4)));
        const f16x8 a1 = *(const f16x8*)(hb + (ra1 << 10) + (cb ^ ((ra1 & 7) << 4)));
        const f16x8 bv = *(const f16x8*)((const char*)Wh_s + (rb << 10) + (cb ^ ((rb & 7) << 4)));
        acc0 = __builtin_amdgcn_mfma_f32_16x16x32_f16(a0, bv, acc0, 0, 0, 0);
        acc1 = __builtin_amdgcn_mfma_f32_16x16x32_f16(a1, bv, acc1, 0, 0, 0);
      }
      // wave-private gate exchange: C (b, n=(g,v)) -> [b][c = v*4+g]; no barrier
      {
        const int n = l & 15;
        const int c = ((n & 3) << 2) + (n >> 2);
#pragma unroll
        for (int r = 0; r < 4; ++r) {
          const int br = ((l >> 4) << 2) + r;
          Gw[br * 20 + c] = acc0[r];
          Gw[(16 + br) * 20 + c] = acc1[r];
        }
      }
      asm volatile("s_waitcnt lgkmcnt(0)" ::: "memory");
      __builtin_amdgcn_sched_barrier(0);
      {
        const float4 ga = *(const float4*)(Gw + b32 * 20 + (vp << 3));      // unit 2vp: i,f,g,o
        const float4 gb = *(const float4*)(Gw + b32 * 20 + (vp << 3) + 4);  // unit 2vp+1
        pi0 = ga.x; pf0 = ga.y; pg0 = ga.z; po0 = ga.w;
        pi1 = gb.x; pf1 = gb.y; pg1 = gb.z; po1 = gb.w;
      }
    }

    pi0 += (float)xc0[0]; pi1 += (float)xc0[1];
    pf0 += (float)xc1[0]; pf1 += (float)xc1[1];
    pg0 += (float)xc2[0]; pg1 += (float)xc2[1];
    po0 += (float)xc3[0]; po1 += (float)xc3[1];

    const float i0 = sigf(pi0), i1 = sigf(pi1);
    const float f0 = sigf(pf0), f1 = sigf(pf1);
    const float g0 = tanh_f(pg0), g1 = tanh_f(pg1);
    const float o0 = sigf(po0), o1 = sigf(po1);
    c0 = f0 * c0 + i0 * g0;
    c1 = f1 * c1 + i1 * g1;
    const float h0v = o0 * tanh_f(c0);
    const float h1v = o1 * tanh_f(c1);

    union { f16x2 h2; unsigned u; } pk;
    pk.h2[0] = (f16)h0v; pk.h2[1] = (f16)h1v;

    // publish h_{t+1}: single 8B atomic {tag = t+1, data} — fire and forget
    {
      const size_t ridx = ((size_t)((t + 1) & 3) << 13) + ((size_t)b32 << 8) + (ug >> 1);
      const unsigned long long pv = ((unsigned long long)pk.u << 32) | (unsigned long long)(t + 1);
      __hip_atomic_store(rdir + ridx, pv, __ATOMIC_RELAXED, __HIP_MEMORY_SCOPE_AGENT);
    }

    // epilogue stores — off the critical path
    const size_t orow = (((size_t)b32 * 512 + (size_t)tau) << 10) + ((size_t)dir << 9) + ug;
    if (layer == 0) {
      *(unsigned*)(h0_all + orow) = pk.u;
    } else {
      *(float2*)(outf + orow) = make_float2(h0v, h1v);
    }
    if (t == 511) {
      const size_t nidx = (((size_t)(layer << 1) + (size_t)dir) << 14) + ((size_t)b32 << 9) + ug;
      *(float2*)(hn + nidx) = make_float2(h0v, h1v);
      *(float2*)(cn + nidx) = make_float2(c0, c1);
    }

    xc0 = xn0; xc1 = xn1; xc2 = xn2; xc3 = xn3;
  }
}

// ---------------- host ----------------
extern "C" void kernel_launch(void* const* d_in, const int* in_sizes, int n_in,
                              void* d_out, int out_size, void* d_ws, size_t ws_size,
                              hipStream_t stream) {
  const float* x = (const float*)d_in[0];
  const float* Wx0 = (const float*)d_in[1];
  const float* Wh0 = (const float*)d_in[2];
  const float* bx0 = (const float*)d_in[3];
  const float* bh0 = (const float*)d_in[4];
  const float* Wx1 = (const float*)d_in[5];
  const float* Wh1 = (const float*)d_in[6];
  const float* bx1 = (const float*)d_in[7];
  const float* bh1 = (const float*)d_in[8];

  char* ws = (char*)d_ws;
  size_t off = 0;
  auto alloc = [&](size_t b) { char* p = ws + off; off += (b + 255) & ~(size_t)255; return p; };
  f16* xg = (f16*)alloc(2ull * 16384 * 2048 * 2);      // 134 MB (reused both layers)
  f16* x_h = (f16*)alloc(16384ull * 512 * 2);
  f16* h0a = (f16*)alloc(16384ull * 1024 * 2);
  f16* Wx0h = (f16*)alloc(2ull * 2048 * 512 * 2);
  f16* Wh0h = (f16*)alloc(2ull * 2048 * 512 * 2);
  f16* Wx1h = (f16*)alloc(2ull * 2048 * 1024 * 2);
  f16* Wh1h = (f16*)alloc(2ull * 2048 * 512 * 2);
  float* bias0 = (float*)alloc(4096 * 4);
  float* bias1 = (float*)alloc(4096 * 4);
  const size_t RB = 2ull * 4 * 32 * 256 * 8;           // 512 KB per layer ring
  unsigned long long* ring0 = (unsigned long long*)alloc(RB);
  unsigned long long* ring1 = (unsigned long long*)alloc(RB);
  if (off > ws_size) return;  // needs ~207 MB of workspace

  float* outp = (float*)d_out;
  float* hn = outp + 16384ull * 1024;
  float* cn = hn + 4ull * 32 * 512;

  // clear ring tags (stale tags from a previous replay would alias epochs)
  hipMemsetAsync(ring0, 0, 2 * RB, stream);

  f2h_kernel<<<dim3(2097152 / 256), 256, 0, stream>>>(x, x_h, 2097152);
  f2h_kernel<<<dim3(524288 / 256), 256, 0, stream>>>(Wx0, Wx0h, 524288);
  f2h_kernel<<<dim3(524288 / 256), 256, 0, stream>>>(Wh0, Wh0h, 524288);
  f2h_kernel<<<dim3(1048576 / 256), 256, 0, stream>>>(Wx1, Wx1h, 1048576);
  f2h_kernel<<<dim3(524288 / 256), 256, 0, stream>>>(Wh1, Wh1h, 524288);
  bias_kernel<<<16, 256, 0, stream>>>(bx0, bh0, bias0, 4096);
  bias_kernel<<<16, 256, 0, stream>>>(bx1, bh1, bias1, 4096);

  dim3 g(128, 32);
  gemm_xg<<<g, 256, 0, stream>>>(x_h, Wx0h, bias0, xg, 512);
  lstm_scan<<<64, 256, 0, stream>>>(Wh0h, xg, ring0, h0a, nullptr, hn, cn, 0);
  gemm_xg<<<g, 256, 0, stream>>>(h0a, Wx1h, bias1, xg, 1024);
  lstm_scan<<<64, 256, 0, stream>>>(Wh1h, xg, ring1, nullptr, outp, hn, cn, 1);
}

// Round 11
// 5144.730 us; speedup vs baseline: 1.7296x; 1.1075x over previous
//
#include <hip/hip_runtime.h>

typedef _Float16 f16;
typedef _Float16 f16x2 __attribute__((ext_vector_type(2)));
typedef _Float16 f16x4 __attribute__((ext_vector_type(4)));
typedef _Float16 f16x8 __attribute__((ext_vector_type(8)));
typedef float f32x4 __attribute__((ext_vector_type(4)));

#define AS1 __attribute__((address_space(1)))
#define AS3 __attribute__((address_space(3)))

static __device__ __forceinline__ float sigf(float x) { return 1.f / (1.f + __expf(-x)); }
static __device__ __forceinline__ float tanh_f(float x) { return 2.f / (1.f + __expf(-2.f * x)) - 1.f; }

// ---------------- fp32 -> fp16 ----------------
__global__ void f2h_kernel(const float* __restrict__ in, f16* __restrict__ out, int n4) {
  const int i = blockIdx.x * blockDim.x + threadIdx.x;
  if (i >= n4) return;
  const float4 v = ((const float4*)in)[i];
  f16x4 o;
  o[0] = (f16)v.x; o[1] = (f16)v.y; o[2] = (f16)v.z; o[3] = (f16)v.w;
  ((f16x4*)out)[i] = o;
}

__global__ void bias_kernel(const float* __restrict__ a, const float* __restrict__ b,
                            float* __restrict__ o, int n) {
  const int i = blockIdx.x * blockDim.x + threadIdx.x;
  if (i < n) o[i] = a[i] + b[i];
}

// ---------------- xg GEMM:  out[dir][row][g] = A[row,:]·Bt[dir*2048+g,:] + bias ----------------
__global__ __launch_bounds__(256) void gemm_xg(const f16* __restrict__ A,
                                               const f16* __restrict__ Bt,
                                               const float* __restrict__ bias,
                                               f16* __restrict__ outp, int K) {
  __shared__ f16 As[128 * 64];
  __shared__ f16 Bs[128 * 64];
  const int tid = threadIdx.x;
  const int w = tid >> 6, l = tid & 63;
  const int m0 = blockIdx.x << 7, n0 = blockIdx.y << 7;
  const int wm = w >> 1, wn = w & 1;
  f32x4 acc[4][4] = {};

  const int lr8 = l >> 3, lc8 = l & 7;
  const int gcol = (lc8 ^ lr8) << 3;

  for (int k0 = 0; k0 < K; k0 += 64) {
    __syncthreads();
#pragma unroll
    for (int j = 0; j < 4; ++j) {
      const int i = (w << 2) + j;
      const f16* ga = A + (size_t)(m0 + (i << 3) + lr8) * K + (k0 + gcol);
      __builtin_amdgcn_global_load_lds((const AS1 void*)ga, (AS3 void*)(As + (i << 9)), 16, 0, 0);
      const f16* gb = Bt + (size_t)(n0 + (i << 3) + lr8) * K + (k0 + gcol);
      __builtin_amdgcn_global_load_lds((const AS1 void*)gb, (AS3 void*)(Bs + (i << 9)), 16, 0, 0);
    }
    asm volatile("s_waitcnt vmcnt(0)" ::: "memory");
    __syncthreads();

#pragma unroll
    for (int kk = 0; kk < 2; ++kk) {
      const int cb = (kk << 6) + ((l >> 4) << 4);
      f16x8 af[4], bf[4];
#pragma unroll
      for (int a = 0; a < 4; ++a) {
        const int r = (wm << 6) + (a << 4) + (l & 15);
        af[a] = *(const f16x8*)((const char*)As + r * 128 + (cb ^ ((r & 7) << 4)));
      }
#pragma unroll
      for (int b = 0; b < 4; ++b) {
        const int r = (wn << 6) + (b << 4) + (l & 15);
        bf[b] = *(const f16x8*)((const char*)Bs + r * 128 + (cb ^ ((r & 7) << 4)));
      }
#pragma unroll
      for (int a = 0; a < 4; ++a)
#pragma unroll
        for (int b = 0; b < 4; ++b)
          acc[a][b] = __builtin_amdgcn_mfma_f32_16x16x32_f16(af[a], bf[b], acc[a][b], 0, 0, 0);
    }
  }

#pragma unroll
  for (int b = 0; b < 4; ++b) {
    const int col = n0 + (wn << 6) + (b << 4) + (l & 15);
    const float bv = bias[col];
    f16* ob = outp + (size_t)(col >> 11) * (16384ull * 2048) + (col & 2047);
#pragma unroll
    for (int a = 0; a < 4; ++a) {
      const int row0 = m0 + (wm << 6) + (a << 4) + ((l >> 4) << 2);
#pragma unroll
      for (int r = 0; r < 4; ++r)
        ob[(size_t)(row0 + r) * 2048] = (f16)(acc[a][b][r] + bv);
    }
  }
}

// ---------------- persistent bidirectional LSTM scan (one layer) ----------------
// grid: 64 WGs = 2 dirs x 32 unit-slices. Wh slice resident in LDS. R3's ring
// protocol: 8B {tag=epoch, data} entries, 4-slot ring, bounded guards, no fences.
// R11 poll = sentinel-gated flat verify:
//  1) burst all 32 entries (R3's opening move; fast case unchanged)
//  2) spin ONLY on chunk 0 (4 entries, one producer WG; sentinels distributed
//     across the slot -> no hot line; 32 B/thread/period while waiting)
//  3) once visible, re-issue ALL stale chunks CONCURRENTLY (1 RT instead of the
//     serial walk's ~7), flat-verify, rare stragglers bounded-loop.
__global__ __launch_bounds__(256) void lstm_scan(const f16* __restrict__ Whb,   // [2][2048][512]
                                                 const f16* __restrict__ xg,    // [2][16384][2048]
                                                 unsigned long long* __restrict__ ring,  // [2][4][32][256]
                                                 f16* __restrict__ h0_all,      // [16384][1024] (layer0)
                                                 float* __restrict__ outf,      // [16384][1024] (layer1)
                                                 float* __restrict__ hn,        // [4][32][512]
                                                 float* __restrict__ cn,        // [4][32][512]
                                                 const int layer) {
  __shared__ f16 Wh_s[64 * 512];      // 64 KB, XOR-swizzled rows
  __shared__ f16 h_s[32 * 512];       // 32 KB, XOR-swizzled rows
  __shared__ float G_s[4 * 32 * 18];  // 9 KB gate exchange, stride 18

  const int tid = threadIdx.x;
  const int dir = blockIdx.x >> 5;
  const int s = blockIdx.x & 31;
  const int w = tid >> 6, l = tid & 63;

  // load Wh slice: local row lr=16g+u <- Whb row dir*2048 + 512g + 16s + u (wave-coalesced)
#pragma unroll
  for (int j = 0; j < 16; ++j) {
    const int chunk = (j << 8) + tid;
    const int lr = chunk >> 6;
    const int cbyte = (chunk & 63) << 4;
    const int g = lr >> 4, u = lr & 15;
    const char* src = (const char*)Whb + (((size_t)dir * 2048 + (g << 9) + (s << 4) + u) << 10) + cbyte;
    const uint4 v = *(const uint4*)src;
    *(uint4*)((char*)Wh_s + (lr << 10) + (cbyte ^ ((lr & 7) << 4))) = v;
  }

  unsigned long long* rdir = ring + ((size_t)dir << 15);  // 4*32*256 entries per dir
  const int bb = tid >> 3;  // batch row 0..31
  const int up = tid & 7;   // unit pair -> units 2up, 2up+1

  float c0 = 0.f, c1 = 0.f;
  __syncthreads();

#pragma unroll 1
  for (int t = 0; t < 512; ++t) {
    const int tau = dir ? (511 - t) : t;
    // xg loads at step start (R3-proven position)
    const f16* xr = xg + (((size_t)dir * 16384 + (size_t)bb * 512 + (size_t)tau) << 11) + (s << 4) + (up << 1);
    const f16x2 xv0 = *(const f16x2*)(xr);
    const f16x2 xv1 = *(const f16x2*)(xr + 512);
    const f16x2 xv2 = *(const f16x2*)(xr + 1024);
    const f16x2 xv3 = *(const f16x2*)(xr + 1536);

    float pi0 = 0.f, pi1 = 0.f, pf0 = 0.f, pf1 = 0.f, pg0 = 0.f, pg1 = 0.f, po0 = 0.f, po1 = 0.f;

    if (t > 0) {
      const unsigned tgt = (unsigned)t;
      const unsigned long long* rs = rdir + ((size_t)(t & 3) << 13);  // slot: 32*256 entries
      unsigned long long v[8][4];
      // (1) optimistic burst: all 32 independent 8B loads
#pragma unroll
      for (int j = 0; j < 8; ++j) {
        const int chunk = (j << 8) + tid;
        const unsigned long long* sp = rs + ((chunk >> 6) << 8) + ((chunk & 63) << 2);
#pragma unroll
        for (int q = 0; q < 4; ++q)
          v[j][q] = __hip_atomic_load(sp + q, __ATOMIC_RELAXED, __HIP_MEMORY_SCOPE_AGENT);
      }
      // (2) sentinel spin: chunk 0 only (covers the visibility window cheaply)
      {
        const unsigned long long* sp = rs + ((tid >> 6) << 8) + ((tid & 63) << 2);
        int guard = 0;
        while (!(((unsigned)v[0][0] == tgt) & ((unsigned)v[0][1] == tgt) &
                 ((unsigned)v[0][2] == tgt) & ((unsigned)v[0][3] == tgt))) {
#pragma unroll
          for (int q = 0; q < 4; ++q)
            v[0][q] = __hip_atomic_load(sp + q, __ATOMIC_RELAXED, __HIP_MEMORY_SCOPE_AGENT);
          if (++guard > (1 << 20)) break;
        }
      }
      // (3) flat verify: re-issue ALL stale chunks concurrently, check, repeat (rare)
      {
        bool ok[8];
        ok[0] = true;
        int remaining = 0;
#pragma unroll
        for (int j = 1; j < 8; ++j) {
          ok[j] = (((unsigned)v[j][0] == tgt) & ((unsigned)v[j][1] == tgt) &
                   ((unsigned)v[j][2] == tgt) & ((unsigned)v[j][3] == tgt));
          remaining += ok[j] ? 0 : 1;
        }
        int guard = 0;
        while (remaining && ++guard <= (1 << 20)) {
#pragma unroll
          for (int j = 1; j < 8; ++j) {
            if (!ok[j]) {
              const int chunk = (j << 8) + tid;
              const unsigned long long* sp = rs + ((chunk >> 6) << 8) + ((chunk & 63) << 2);
#pragma unroll
              for (int q = 0; q < 4; ++q)
                v[j][q] = __hip_atomic_load(sp + q, __ATOMIC_RELAXED, __HIP_MEMORY_SCOPE_AGENT);
            }
          }
#pragma unroll
          for (int j = 1; j < 8; ++j) {
            if (!ok[j]) {
              if (((unsigned)v[j][0] == tgt) & ((unsigned)v[j][1] == tgt) &
                  ((unsigned)v[j][2] == tgt) & ((unsigned)v[j][3] == tgt)) {
                ok[j] = true;
                --remaining;
              }
            }
          }
        }
      }
      // stage to LDS (XOR-swizzled)
#pragma unroll
      for (int j = 0; j < 8; ++j) {
        const int chunk = (j << 8) + tid;
        const int b = chunk >> 6;
        uint4 d;
        d.x = (unsigned)(v[j][0] >> 32);
        d.y = (unsigned)(v[j][1] >> 32);
        d.z = (unsigned)(v[j][2] >> 32);
        d.w = (unsigned)(v[j][3] >> 32);
        const int cbyte = (chunk & 63) << 4;
        *(uint4*)((char*)h_s + (b << 10) + (cbyte ^ ((b & 7) << 4))) = d;
      }
      __syncthreads();

      // G[b, 16w+u] = sum_k h[b,k] * WhS[16w+u, k]   (wave w owns gate w)
      f32x4 acc0 = {}, acc1 = {};
#pragma unroll
      for (int kk = 0; kk < 16; ++kk) {
        const int cb = (kk << 6) + ((l >> 4) << 4);
        const int ra0 = l & 15;
        const int ra1 = 16 + ra0;
        const int rb = (w << 4) + ra0;
        const f16x8 a0 = *(const f16x8*)((const char*)h_s + (ra0 << 10) + (cb ^ ((ra0 & 7) << 4)));
        const f16x8 a1 = *(const f16x8*)((const char*)h_s + (ra1 << 10) + (cb ^ ((ra1 & 7) << 4)));
        const f16x8 bv = *(const f16x8*)((const char*)Wh_s + (rb << 10) + (cb ^ ((rb & 7) << 4)));
        acc0 = __builtin_amdgcn_mfma_f32_16x16x32_f16(a0, bv, acc0, 0, 0, 0);
        acc1 = __builtin_amdgcn_mfma_f32_16x16x32_f16(a1, bv, acc1, 0, 0, 0);
      }
#pragma unroll
      for (int r = 0; r < 4; ++r) {
        const int dr = ((l >> 4) << 2) + r;
        G_s[((w << 5) + dr) * 18 + (l & 15)] = acc0[r];
        G_s[((w << 5) + 16 + dr) * 18 + (l & 15)] = acc1[r];
      }
      __syncthreads();

      const float* gp = G_s + bb * 18 + (up << 1);
      const float2 vi = *(const float2*)(gp);
      const float2 vf = *(const float2*)(gp + 576);
      const float2 vg = *(const float2*)(gp + 1152);
      const float2 vo = *(const float2*)(gp + 1728);
      pi0 = vi.x; pi1 = vi.y; pf0 = vf.x; pf1 = vf.y;
      pg0 = vg.x; pg1 = vg.y; po0 = vo.x; po1 = vo.y;
    }

    pi0 += (float)xv0[0]; pi1 += (float)xv0[1];
    pf0 += (float)xv1[0]; pf1 += (float)xv1[1];
    pg0 += (float)xv2[0]; pg1 += (float)xv2[1];
    po0 += (float)xv3[0]; po1 += (float)xv3[1];

    const float i0 = sigf(pi0), i1 = sigf(pi1);
    const float f0 = sigf(pf0), f1 = sigf(pf1);
    const float g0 = tanh_f(pg0), g1 = tanh_f(pg1);
    const float o0 = sigf(po0), o1 = sigf(po1);
    c0 = f0 * c0 + i0 * g0;
    c1 = f1 * c1 + i1 * g1;
    const float h0v = o0 * tanh_f(c0);
    const float h1v = o1 * tanh_f(c1);

    union { f16x2 h2; unsigned u; } pk;
    pk.h2[0] = (f16)h0v; pk.h2[1] = (f16)h1v;

    // publish h_{t+1}: single 8B atomic {tag = t+1, data} — fire and forget
    {
      const size_t ridx = ((size_t)((t + 1) & 3) << 13) + ((size_t)bb << 8) + (s << 3) + up;
      const unsigned long long pv = ((unsigned long long)pk.u << 32) | (unsigned long long)(t + 1);
      __hip_atomic_store(rdir + ridx, pv, __ATOMIC_RELAXED, __HIP_MEMORY_SCOPE_AGENT);
    }

    // epilogue stores — off the critical path
    const size_t orow = (((size_t)bb * 512 + (size_t)tau) << 10) + ((size_t)dir << 9) + (s << 4) + (up << 1);
    if (layer == 0) {
      *(unsigned*)(h0_all + orow) = pk.u;
    } else {
      *(float2*)(outf + orow) = make_float2(h0v, h1v);
    }
    if (t == 511) {
      const size_t nidx = (((size_t)(layer << 1) + (size_t)dir) << 14) + ((size_t)bb << 9) + (s << 4) + (up << 1);
      *(float2*)(hn + nidx) = make_float2(h0v, h1v);
      *(float2*)(cn + nidx) = make_float2(c0, c1);
    }
  }
}

// ---------------- host ----------------
extern "C" void kernel_launch(void* const* d_in, const int* in_sizes, int n_in,
                              void* d_out, int out_size, void* d_ws, size_t ws_size,
                              hipStream_t stream) {
  const float* x = (const float*)d_in[0];
  const float* Wx0 = (const float*)d_in[1];
  const float* Wh0 = (const float*)d_in[2];
  const float* bx0 = (const float*)d_in[3];
  const float* bh0 = (const float*)d_in[4];
  const float* Wx1 = (const float*)d_in[5];
  const float* Wh1 = (const float*)d_in[6];
  const float* bx1 = (const float*)d_in[7];
  const float* bh1 = (const float*)d_in[8];

  char* ws = (char*)d_ws;
  size_t off = 0;
  auto alloc = [&](size_t b) { char* p = ws + off; off += (b + 255) & ~(size_t)255; return p; };
  f16* xg = (f16*)alloc(2ull * 16384 * 2048 * 2);      // 134 MB (reused both layers)
  f16* x_h = (f16*)alloc(16384ull * 512 * 2);
  f16* h0a = (f16*)alloc(16384ull * 1024 * 2);
  f16* Wx0h = (f16*)alloc(2ull * 2048 * 512 * 2);
  f16* Wh0h = (f16*)alloc(2ull * 2048 * 512 * 2);
  f16* Wx1h = (f16*)alloc(2ull * 2048 * 1024 * 2);
  f16* Wh1h = (f16*)alloc(2ull * 2048 * 512 * 2);
  float* bias0 = (float*)alloc(4096 * 4);
  float* bias1 = (float*)alloc(4096 * 4);
  const size_t RB = 2ull * 4 * 32 * 256 * 8;           // 512 KB per layer ring
  unsigned long long* ring0 = (unsigned long long*)alloc(RB);
  unsigned long long* ring1 = (unsigned long long*)alloc(RB);
  if (off > ws_size) return;  // needs ~207 MB of workspace

  float* outp = (float*)d_out;
  float* hn = outp + 16384ull * 1024;
  float* cn = hn + 4ull * 32 * 512;

  // clear ring tags (stale tags from a previous replay would alias epochs)
  hipMemsetAsync(ring0, 0, 2 * RB, stream);

  f2h_kernel<<<dim3(2097152 / 256), 256, 0, stream>>>(x, x_h, 2097152);
  f2h_kernel<<<dim3(524288 / 256), 256, 0, stream>>>(Wx0, Wx0h, 524288);
  f2h_kernel<<<dim3(524288 / 256), 256, 0, stream>>>(Wh0, Wh0h, 524288);
  f2h_kernel<<<dim3(1048576 / 256), 256, 0, stream>>>(Wx1, Wx1h, 1048576);
  f2h_kernel<<<dim3(524288 / 256), 256, 0, stream>>>(Wh1, Wh1h, 524288);
  bias_kernel<<<16, 256, 0, stream>>>(bx0, bh0, bias0, 4096);
  bias_kernel<<<16, 256, 0, stream>>>(bx1, bh1, bias1, 4096);

  dim3 g(128, 32);
  gemm_xg<<<g, 256, 0, stream>>>(x_h, Wx0h, bias0, xg, 512);
  lstm_scan<<<64, 256, 0, stream>>>(Wh0h, xg, ring0, h0a, nullptr, hn, cn, 0);
  gemm_xg<<<g, 256, 0, stream>>>(h0a, Wx1h, bias1, xg, 1024);
  lstm_scan<<<64, 256, 0, stream>>>(Wh1h, xg, ring1, nullptr, outp, hn, cn, 1);
}